// Round 6
// baseline (297.302 us; speedup 1.0000x reference)
//
#include <hip/hip_runtime.h>
#include <hip/hip_bf16.h>
#include <math.h>

typedef __bf16 bf16;
typedef __bf16 bf16x4 __attribute__((ext_vector_type(4)));
typedef __bf16 bf16x8 __attribute__((ext_vector_type(8)));
typedef float f32x4 __attribute__((ext_vector_type(4)));

#define OCC 230
#define NRELS 53
// ws layout (bf16 elem offsets)
#define W2V48_OFF 0        // 50000 x 48  (dims 0..47, 96B rows)
#define WTAIL_OFF 2400000  // 50000 x 4   [d48, d49, 0, 0]
#define PCAT_OFF  2600000  // 3721 x 16   [p1 x5, p2 x5, 0 x6]
#define REMBB_OFF 2659536  // 64 x 704    (rows>=53, cols>=690 zero)
#define CONVB_OFF 2704592  // 256 x 192   (permuted K', oc>=230 zero)
#define ZOFF      2753744  // 8 zeros

union FragU { bf16x8 v8; bf16x4 v4[2]; bf16 e[8]; };

// K' permutation: k' = tap*64 + j ; j<48 -> d=j (W plane); j 48..59 -> T dims; j>=60 pad
__device__ __host__ inline int jmap(int j) {
  if (j < 48) return j;
  if (j < 53) return 50 + (j - 48);   // p1 d0..4
  if (j < 56) return 55 + (j - 53);   // p2 d0..2
  if (j < 58) return 58 + (j - 56);   // p2 d3..4
  if (j < 60) return 48 + (j - 58);   // w2v d48..49
  return -1;                          // pad
}

// ---- prep: build bf16 tables in ws ----
__global__ void pcnn_prep(const float* __restrict__ w2v, const float* __restrict__ p1e,
                          const float* __restrict__ p2e, const float* __restrict__ remb,
                          const float* __restrict__ convw, bf16* __restrict__ wsb) {
  const int i = blockIdx.x * 256 + threadIdx.x;
  if (i < 300000) {                       // w2v48: 8 elems per thread
    const int w = i / 6, c = i - 6 * w;
    const float* s = w2v + w * 50 + c * 8;
    bf16* d = wsb + W2V48_OFF + w * 48 + c * 8;
#pragma unroll
    for (int jj = 0; jj < 8; ++jj) d[jj] = (bf16)s[jj];
    return;
  }
  int e = i - 300000;
  if (e < 50000) {                        // wtail
    bf16* d = wsb + WTAIL_OFF + e * 4;
    d[0] = (bf16)w2v[e * 50 + 48];
    d[1] = (bf16)w2v[e * 50 + 49];
    d[2] = (bf16)0.f; d[3] = (bf16)0.f;
    return;
  }
  e -= 50000;
  if (e < 59536) {                        // pcat16
    const int row = e >> 4, c = e & 15;
    const int v1 = row / 61, v2 = row - v1 * 61;
    float v = 0.f;
    if (c < 5) v = p1e[v1 * 5 + c];
    else if (c < 10) v = p2e[v2 * 5 + (c - 5)];
    wsb[PCAT_OFF + e] = (bf16)v;
    return;
  }
  e -= 59536;
  if (e < 45056) {                        // rembb [64][704]
    const int r = e / 704, c = e - r * 704;
    wsb[REMBB_OFF + e] = (r < NRELS && c < 690) ? (bf16)remb[r * 690 + c] : (bf16)0.f;
    return;
  }
  e -= 45056;
  if (e < 49152) {                        // convb [256][192] permuted
    const int oc = e / 192, kp = e - oc * 192;
    const int tap = kp >> 6, j = kp & 63;
    const int d = jmap(j);
    wsb[CONVB_OFF + e] = (oc < OCC && d >= 0) ? (bf16)convw[oc * 180 + tap * 60 + d]
                                              : (bf16)0.f;
    return;
  }
  e -= 49152;
  if (e < 8) wsb[ZOFF + e] = (bf16)0.f;
}

// LDS x-buffer: per buf = W[128][56] (7168) + TA[128][8] (1024) + TB[128][8] (1024)
#define WPL 0
#define TAPL 7168
#define TBPL 8192
#define BUFE 9216

__global__ __launch_bounds__(1024, 4)
void pcnn_bag(const int* __restrict__ words, const int* __restrict__ posi,
              const float* __restrict__ cb0, const float* __restrict__ cb1,
              const float* __restrict__ cb2, const float* __restrict__ rbias,
              const bf16* __restrict__ wsb, float* __restrict__ out)
{
  __shared__ __align__(16) bf16 xpl[2][BUFE];
  __shared__ __align__(16) bf16 fl_all[8][712];
  __shared__ int widx[960];                       // word | pidx<<16 | piece<<28
  __shared__ float poolbuf[2][3][256];
  __shared__ float logits_l[8][64];

  const int t = threadIdx.x;
  const int b = blockIdx.x;
  const int wv = t >> 6;       // 0..15
  const int lane = t & 63;
  const int g = lane >> 4;
  const int cl = lane & 15;
  const int mh = wv >> 3;      // m-half
  const int ocp = wv & 7;      // oc-pair

  // ---- ids for the whole bag ----
  if (t < 960) {
    const int w = words[b * 960 + t];
    const int2 pp = *reinterpret_cast<const int2*>(posi + b * 1920 + 2 * t);
    const bool b0 = pp.x >= 30, b1 = pp.y >= 30;
    const int pc = (b0 && b1) ? 0 : ((!b0 && !b1) ? 2 : 1);
    widx[t] = w | ((pp.x * 61 + pp.y) << 16) | (pc << 28);
  }
  if (t < 112) fl_all[t / 14][690 + (t % 14)] = (bf16)0.0f;

  // ---- conv weights (pre-permuted bf16) -> registers: 12 frags ----
  FragU Bf[2][6];
  {
    const bf16* cwb = wsb + CONVB_OFF;
#pragma unroll
    for (int nt = 0; nt < 2; ++nt) {
      const int oc = ocp * 32 + nt * 16 + cl;
#pragma unroll
      for (int ks = 0; ks < 6; ++ks)
        Bf[nt][ks].v8 = *reinterpret_cast<const bf16x8*>(cwb + oc * 192 + ks * 32 + g * 8);
    }
  }

  // ---- per-thread bias/slot precompute for combine phase ----
  int pA = 0, ocA = 0;
  float biasA = 0.0f;
  if (t < 690) {
    pA = t / 230; ocA = t - pA * 230;
    biasA = (pA == 0 ? cb0 : pA == 1 ? cb1 : cb2)[ocA];
  }

  // ---- gather slot precompute (per thread, constant across sentences) ----
  const int wslot = wv * 64 + lane;          // W: waves 0..13, slots 0..895
  const int wlr = wslot / 7;
  const int wc  = wslot - 7 * wlr;
  const int taslot = (wv - 14) * 64 + lane;  // TA: waves 14,15 -> lr 0..127
  const int tbslot = wv * 64 + lane;         // TB: waves 0..7, slots 0..511
  const int tblr = tbslot >> 2;
  const int tbp  = tbslot & 3;

  __syncthreads();  // widx ready

  auto issue_gather = [&](int s, int nb) {
    bf16* bufb = &xpl[nb][0];
    const int* wrow = &widx[s * 120];
    if (wv < 14) {            // W plane, 16B
      const bf16* src = wsb + ZOFF;
      if (wlr >= 1 && wlr <= 120 && wc < 6) {
        const int wi = wrow[wlr - 1];
        src = wsb + W2V48_OFF + (wi & 0xFFFF) * 48 + wc * 8;
      }
      bf16* dst = bufb + WPL + wv * 512;
      __builtin_amdgcn_global_load_lds(
          (const __attribute__((address_space(1))) void*)src,
          (__attribute__((address_space(3))) void*)dst, 16, 0, 0);
    } else {                  // TA plane, 16B
      const bf16* src = wsb + ZOFF;
      if (taslot >= 1 && taslot <= 120) {
        const int wi = wrow[taslot - 1];
        src = wsb + PCAT_OFF + (((unsigned)wi >> 16) & 0xFFF) * 16;
      }
      bf16* dst = bufb + TAPL + (wv - 14) * 512;
      __builtin_amdgcn_global_load_lds(
          (const __attribute__((address_space(1))) void*)src,
          (__attribute__((address_space(3))) void*)dst, 16, 0, 0);
    }
    if (wv < 8) {             // TB plane, 4B
      const bf16* src = wsb + ZOFF;
      if (tblr >= 1 && tblr <= 120) {
        const int wi = wrow[tblr - 1];
        if (tbp == 0)      src = wsb + PCAT_OFF + (((unsigned)wi >> 16) & 0xFFF) * 16 + 8;
        else if (tbp == 1) src = wsb + WTAIL_OFF + (wi & 0xFFFF) * 4;
      }
      bf16* dst = bufb + TBPL + wv * 128;
      __builtin_amdgcn_global_load_lds(
          (const __attribute__((address_space(1))) void*)src,
          (__attribute__((address_space(3))) void*)dst, 4, 0, 0);
    }
  };

  issue_gather(0, 0);
  asm volatile("s_waitcnt vmcnt(0)" ::: "memory");
  __syncthreads();

  int lrb[4];
#pragma unroll
  for (int mt = 0; mt < 4; ++mt) {
    const int m = mh * 64 + mt * 16 + cl;
    lrb[mt] = (m < 120 ? m : 119);
  }

  // ---- per-sentence: conv GEMM + piecewise pool + tanh ----
  for (int s = 0; s < 8; ++s) {
    const int nb = s & 1;
    if (s < 7) issue_gather(s + 1, nb ^ 1);

    f32x4 acc[4][2];
    const f32x4 z4 = {0.f, 0.f, 0.f, 0.f};
#pragma unroll
    for (int mt = 0; mt < 4; ++mt) { acc[mt][0] = z4; acc[mt][1] = z4; }

    const char* bufc = reinterpret_cast<const char*>(&xpl[nb][0]);
#pragma unroll
    for (int ks = 0; ks < 6; ++ks) {
      const int k0 = ks * 32 + g * 8;
      const int tap = k0 >> 6;
      const int j = k0 & 63;
#pragma unroll
      for (int mt = 0; mt < 4; ++mt) {
        const int lr = lrb[mt] + tap;
        const int boff = (j < 48) ? (lr * 112 + j * 2)
                                  : ((j == 48 ? (TAPL * 2) : (TBPL * 2)) + lr * 16);
        FragU a;
        a.v8 = *reinterpret_cast<const bf16x8*>(bufc + boff);
#pragma unroll
        for (int nt = 0; nt < 2; ++nt)
          acc[mt][nt] = __builtin_amdgcn_mfma_f32_16x16x32_bf16(
              a.v8, Bf[nt][ks].v8, acc[mt][nt], 0, 0, 0);
      }
    }

    // piecewise masked max (ref semantics: masked-out contributes 0)
    float pool[2][3];
#pragma unroll
    for (int nt = 0; nt < 2; ++nt) { pool[nt][0] = pool[nt][1] = pool[nt][2] = -INFINITY; }
#pragma unroll
    for (int mt = 0; mt < 4; ++mt) {
      const int l0 = mh * 64 + mt * 16 + g * 4;
      if (l0 < 120) {
        const int4 pv = *reinterpret_cast<const int4*>(&widx[s * 120 + l0]);
        const int pcs[4] = {(int)((unsigned)pv.x >> 28), (int)((unsigned)pv.y >> 28),
                            (int)((unsigned)pv.z >> 28), (int)((unsigned)pv.w >> 28)};
#pragma unroll
        for (int r = 0; r < 4; ++r) {
          const int p = pcs[r];
#pragma unroll
          for (int nt = 0; nt < 2; ++nt) {
            const float v = acc[mt][nt][r];
            pool[nt][0] = fmaxf(pool[nt][0], p == 0 ? v : 0.0f);
            pool[nt][1] = fmaxf(pool[nt][1], p == 1 ? v : 0.0f);
            pool[nt][2] = fmaxf(pool[nt][2], p == 2 ? v : 0.0f);
          }
        }
      }
    }
#pragma unroll
    for (int nt = 0; nt < 2; ++nt)
#pragma unroll
      for (int p = 0; p < 3; ++p) {
        float x = pool[nt][p];
        x = fmaxf(x, __shfl_xor(x, 16));
        x = fmaxf(x, __shfl_xor(x, 32));
        pool[nt][p] = x;
      }
    if (g == 0) {
#pragma unroll
      for (int nt = 0; nt < 2; ++nt) {
        const int oc = ocp * 32 + nt * 16 + cl;
        poolbuf[mh][0][oc] = pool[nt][0];
        poolbuf[mh][1][oc] = pool[nt][1];
        poolbuf[mh][2][oc] = pool[nt][2];
      }
    }
    __syncthreads();  // poolbuf ready

    if (t < 690)
      fl_all[s][t] = (bf16)tanhf(fmaxf(poolbuf[0][pA][ocA], poolbuf[1][pA][ocA]) + biasA);

    asm volatile("s_waitcnt vmcnt(0)" ::: "memory");  // gather(s+1) landed (per wave)
    __syncthreads();  // buffer handoff, poolbuf free, fl_all[s] visible
  }

  // ---- batched logits GEMM: [8 sent x 704] @ rembb^T[704 x 64] ----
  if (wv < 4) {
    f32x4 lac = {0.f, 0.f, 0.f, 0.f};
    const bf16* brow = wsb + REMBB_OFF + (wv * 16 + cl) * 704 + g * 8;
    const bf16x8 zf = {(bf16)0.f, (bf16)0.f, (bf16)0.f, (bf16)0.f,
                       (bf16)0.f, (bf16)0.f, (bf16)0.f, (bf16)0.f};
#pragma unroll
    for (int ks = 0; ks < 22; ++ks) {
      bf16x8 afr = (cl < 8)
          ? *reinterpret_cast<const bf16x8*>(&fl_all[cl][ks * 32 + g * 8]) : zf;
      const bf16x8 bfr = *reinterpret_cast<const bf16x8*>(brow + ks * 32);
      lac = __builtin_amdgcn_mfma_f32_16x16x32_bf16(afr, bfr, lac, 0, 0, 0);
    }
    if (g < 2) {
      const int rel = wv * 16 + cl;
      const float bias = (rel < NRELS) ? rbias[rel] : 0.0f;
#pragma unroll
      for (int r = 0; r < 4; ++r)
        logits_l[g * 4 + r][rel] = lac[r] * 0.5f + bias;
    }
  }
  __syncthreads();

  // ---- per-wave softmax ----
  if (wv < 8) {
    const float x = (lane < NRELS) ? logits_l[wv][lane] : -INFINITY;
    float m = x;
#pragma unroll
    for (int off = 32; off; off >>= 1) m = fmaxf(m, __shfl_xor(m, off));
    const float e = (lane < NRELS) ? __expf(x - m) : 0.0f;
    float sm = e;
#pragma unroll
    for (int off = 32; off; off >>= 1) sm += __shfl_xor(sm, off);
    if (lane < NRELS) logits_l[wv][lane] = x - m - __logf(sm);
  }
  __syncthreads();

  // ---- fused bag-max ----
  if (t < NRELS) {
    float m = logits_l[0][t];
#pragma unroll
    for (int s2 = 1; s2 < 8; ++s2) m = fmaxf(m, logits_l[s2][t]);
    out[b * NRELS + t] = m;
  }
}

extern "C" void kernel_launch(void* const* d_in, const int* in_sizes, int n_in,
                              void* d_out, int out_size, void* d_ws, size_t ws_size,
                              hipStream_t stream) {
  const int* words  = (const int*)d_in[0];
  const int* posi   = (const int*)d_in[1];
  const float* w2v  = (const float*)d_in[2];
  const float* p1e  = (const float*)d_in[3];
  const float* p2e  = (const float*)d_in[4];
  const float* cw   = (const float*)d_in[5];
  const float* cb0  = (const float*)d_in[6];
  const float* cb1  = (const float*)d_in[7];
  const float* cb2  = (const float*)d_in[8];
  const float* remb = (const float*)d_in[9];
  const float* rbias= (const float*)d_in[10];
  bf16* wsb = (bf16*)d_ws;
  float* out = (float*)d_out;

  pcnn_prep<<<1968, 256, 0, stream>>>(w2v, p1e, p2e, remb, cw, wsb);
  pcnn_bag<<<1000, 1024, 0, stream>>>(words, posi, cb0, cb1, cb2, rbias, wsb, out);
}